// Round 12
// baseline (183.435 us; speedup 1.0000x reference)
//
#include <hip/hip_runtime.h>
#include <hip/hip_bf16.h>
#include <stdint.h>

#define B_  2
#define S_  2048
#define D_  1024
#define H_  16
#define DH_ 64

typedef __attribute__((ext_vector_type(8))) __bf16    bf16x8;
typedef __attribute__((ext_vector_type(8))) _Float16  f16x8;
typedef __attribute__((ext_vector_type(4))) _Float16  f16x4;
typedef __attribute__((ext_vector_type(2))) __fp16    fp16x2;   // cvt_pkrtz return type
typedef __attribute__((ext_vector_type(4))) float     f32x4;

__device__ inline unsigned short f2bf(float f) {
    union { float f; uint32_t u; } v; v.f = f;
    uint32_t r = (v.u + 0x7fffu + ((v.u >> 16) & 1u)) >> 16;
    return (unsigned short)r;
}

// async global->LDS, 16B per lane. LDS dest = wave-uniform base + lane*16.
__device__ __forceinline__ void g2l16(const unsigned short* g, unsigned short* l) {
    __builtin_amdgcn_global_load_lds(
        (const __attribute__((address_space(1))) unsigned int*)g,
        (__attribute__((address_space(3))) unsigned int*)l,
        16, 0, 0);
}

// ---------------- merged prep: convert x + transpose weights (R20/R21) ----------------
// R21 BUGFIX: convert partition needs B*S*D/4/256 = 4096 blocks (R20 had
// 2048 -> batch 1 of xb never converted, absmax 0.084). Grid = 4096 + 4096.
__global__ void prep(const float* __restrict__ x, unsigned short* __restrict__ xb,
                     const float* __restrict__ s0, const float* __restrict__ s1,
                     const float* __restrict__ s2, const float* __restrict__ s3,
                     unsigned short* __restrict__ d0, unsigned short* __restrict__ d1,
                     unsigned short* __restrict__ d2, unsigned short* __restrict__ d3)
{
    __shared__ float tile[32][33];
    int bid = blockIdx.x, tid = threadIdx.x;
    if (bid < 4096) {
        int i = (bid * 256 + tid) * 4;
        float4 v = *(const float4*)(x + i);
        ushort4 o;
        o.x = f2bf(v.x); o.y = f2bf(v.y); o.z = f2bf(v.z); o.w = f2bf(v.w);
        *(ushort4*)(xb + i) = o;
    } else {
        int tb = bid - 4096;
        int z = tb >> 10, t = tb & 1023;
        int bx = t & 31, by = t >> 5;
        const float* src; unsigned short* dst;
        switch (z) {
            case 0: src = s0; dst = d0; break;
            case 1: src = s1; dst = d1; break;
            case 2: src = s2; dst = d2; break;
            default: src = s3; dst = d3; break;
        }
        int n0 = bx * 32, k0 = by * 32;
        int tx = tid & 31, ty = tid >> 5;   // (32, 8)
        for (int j = 0; j < 32; j += 8)
            tile[ty + j][tx] = src[(long)(k0 + ty + j) * 1024 + n0 + tx];
        __syncthreads();
        for (int j = 0; j < 32; j += 8)
            dst[(long)(n0 + ty + j) * 1024 + k0 + tx] = f2bf(tile[tx][ty + j]);
    }
}

// ---------------- 128x128 MFMA GEMM (gemm0), in-block split-K (R20) ----------------
// gemm0 experiment record: single-BK64-4wave = 52.7 (prev best), dbuf-BK64 =
// 60.7, dbuf-BK32 = 62.6, retile-128x64 = 58-62. All kept 4 waves/block.
// R20: SAME tile/staging/LDS/barriers, but 8 waves: waves 0-3 compute ks=0
// (k-chunks 0..3 of each BK=64 step), waves 4-7 ks=1, each acc[4][4] partial.
// Total LDS reads/block/iter UNCHANGED (64 x b128); MFMA-per-staged-byte
// UNCHANGED; VGPR ~116 <= 128 -> 4 waves/SIMD -> 2 blocks x 8 = 16 waves/CU
// (50%) vs 10 (30%): pure occupancy gain, the one untried axis.
// Epilogue: ks-partials combined via 4 passes through dead LDS (stride-66
// fp32 overlay, 16.9KB), then the usual Q/K/V scatter.
// Scatter -> Q bf16 (PRE-SCALED 0.125*log2e), K bf16 (PRE-SCALED fw[s]),
// Vt[B,H,64,S] fp16 with half-swap s^((d&8)?4:0) (R13 attn bank fix).
__global__ __launch_bounds__(512, 4)
void gemm128(const unsigned short* __restrict__ A, const unsigned short* __restrict__ Bt,
             unsigned short* __restrict__ Qo, unsigned short* __restrict__ Ko,
             unsigned short* __restrict__ Vt,
             const float* __restrict__ fw)
{
    __shared__ __align__(16) unsigned short Smem[2][128 * 64];   // [0]=A, [1]=B
    unsigned short* As = &Smem[0][0];
    unsigned short* Bs = &Smem[1][0];
    const int tid  = threadIdx.x;
    const int lane = tid & 63, wid = tid >> 6;     // wid in {0..7}
    const int quad = lane >> 4, l15 = lane & 15;
    const int ks   = wid >> 2;                      // K-half this wave computes
    const int wm   = (wid >> 1) & 1, wn = wid & 1;  // 64x64 output quadrant
    const int bm = blockIdx.y, bn = blockIdx.x;
    const int K = 1024;
    f32x4 acc[4][4] = {};
    const long Abase = (long)bm * 128 * K;
    const long Bbase = (long)bn * 128 * K;

    for (int k0 = 0; k0 < K; k0 += 64) {
        __syncthreads();
        // A: 1024 chunks of 16B over 8 waves x 2 rounds
#pragma unroll
        for (int i = 0; i < 2; i++) {
            int base = i * 512 + wid * 64;
            int slot = base + lane;
            int row = slot >> 3, cp = slot & 7;
            int c = cp ^ (row & 7);
            g2l16(A + Abase + (long)row * K + k0 + c * 8, &As[base * 8]);
        }
        // B: 1024 chunks
#pragma unroll
        for (int i = 0; i < 2; i++) {
            int base = i * 512 + wid * 64;
            int slot = base + lane;
            int row = slot >> 3, cp = slot & 7;
            int c = cp ^ (row & 7);
            g2l16(Bt + Bbase + (long)row * K + k0 + c * 8, &Bs[base * 8]);
        }
        __syncthreads();
        bf16x8 af[4], bfr[4];
#pragma unroll
        for (int t = 0; t < 4; t++) {
            int ra = wm * 64 + t * 16 + l15;
            af[t]  = *(const bf16x8*)(As + ra * 64 + (((ks * 4 + quad) ^ (l15 & 7))) * 8);
            int rb = wn * 64 + t * 16 + l15;
            bfr[t] = *(const bf16x8*)(Bs + rb * 64 + (((ks * 4 + quad) ^ (l15 & 7))) * 8);
        }
#pragma unroll
        for (int tm = 0; tm < 4; tm++)
#pragma unroll
            for (int tn = 0; tn < 4; tn++)
                acc[tm][tn] = __builtin_amdgcn_mfma_f32_16x16x32_bf16(af[tm], bfr[tn], acc[tm][tn], 0, 0, 0);
    }

    __syncthreads();   // all LDS reads of the last tile complete -> overlay safe

    // combine ks-partials through dead LDS: 4 passes (one per tm), slot =
    // quadrant id (wm*2+wn), layout [4][16][66] fp32 = 16.9 KB.
    float* ov = (float*)&Smem[0][0];
    const int slot = wm * 2 + wn;
    const float Cq = 0.125f * 1.44269504f;   // score scale * log2(e), folded into Q

#pragma unroll
    for (int p = 0; p < 4; p++) {
        if (ks == 1) {
#pragma unroll
            for (int tn = 0; tn < 4; tn++)
#pragma unroll
                for (int r = 0; r < 4; r++)
                    ov[((slot * 16) + quad * 4 + r) * 66 + tn * 16 + l15] = acc[p][tn][r];
        }
        __syncthreads();
        if (ks == 0) {
#pragma unroll
            for (int tn = 0; tn < 4; tn++)
#pragma unroll
                for (int r = 0; r < 4; r++) {
                    float v = acc[p][tn][r] + ov[((slot * 16) + quad * 4 + r) * 66 + tn * 16 + l15];
                    int gm = bm * 128 + wm * 64 + p * 16 + quad * 4 + r;
                    int gn = bn * 128 + wn * 64 + tn * 16 + l15;
                    int b = gm >> 11, s = gm & 2047;
                    if (gn < 1024) {
                        int h = gn >> 6, d = gn & 63;
                        Qo[(((long)(b * H_ + h) * S_ + s) << 6) + d] = f2bf(v * Cq);
                    } else if (gn < 2048) {
                        int g = gn - 1024; int h = g >> 6, d = g & 63;
                        Ko[(((long)(b * H_ + h) * S_ + s) << 6) + d] = f2bf(v * fw[s]);
                    } else {
                        int g = gn - 2048; int h = g >> 6, d = g & 63;
                        union { _Float16 h; unsigned short u; } cv;
                        cv.h = (_Float16)v;                       // V^T stored FP16
                        int sp = s ^ ((d & 8) ? 4 : 0);           // R13 half-swap involution
                        Vt[((long)(b * H_ + h) * DH_ + d) * S_ + sp] = cv.u;
                    }
                }
        }
        __syncthreads();
    }
}

// ---------------- 64x64 MFMA GEMM (gemm1 / Wo projection), single-buffer ----------------
// R18: 64x64 tile -> grid (16,64) = 1024 blocks = 4+ blocks/CU. LDS 16KB.
__global__ __launch_bounds__(256, 4)
void gemm_wo(const unsigned short* __restrict__ A, const unsigned short* __restrict__ Bt,
             float* __restrict__ Cout)
{
    __shared__ __align__(16) unsigned short As[64 * 64];
    __shared__ __align__(16) unsigned short Bs[64 * 64];
    const int tid  = threadIdx.x;
    const int lane = tid & 63, wid = tid >> 6;
    const int quad = lane >> 4, l15 = lane & 15;
    const int bm = blockIdx.y, bn = blockIdx.x;
    const int K = 1024;
    f32x4 acc[4] = {};
    const long Abase = (long)bm * 64 * K;
    const long Bbase = (long)bn * 64 * K;

    for (int k0 = 0; k0 < K; k0 += 64) {
        __syncthreads();
#pragma unroll
        for (int i = 0; i < 2; i++) {
            int base = i * 256 + wid * 64;
            int slot = base + lane;
            int row = slot >> 3, cp = slot & 7;
            int c = cp ^ (row & 7);
            g2l16(A + Abase + (long)row * K + k0 + c * 8, &As[base * 8]);
        }
#pragma unroll
        for (int i = 0; i < 2; i++) {
            int base = i * 256 + wid * 64;
            int slot = base + lane;
            int row = slot >> 3, cp = slot & 7;
            int c = cp ^ (row & 7);
            g2l16(Bt + Bbase + (long)row * K + k0 + c * 8, &Bs[base * 8]);
        }
        __syncthreads();
#pragma unroll
        for (int ks = 0; ks < 2; ks++) {
            bf16x8 af, bfr[4];
            {
                int ra = wid * 16 + l15;
                af = *(const bf16x8*)(As + ra * 64 + (((ks * 4 + quad) ^ (l15 & 7))) * 8);
            }
#pragma unroll
            for (int tt = 0; tt < 4; tt++) {
                int rb = tt * 16 + l15;
                bfr[tt] = *(const bf16x8*)(Bs + rb * 64 + (((ks * 4 + quad) ^ (l15 & 7))) * 8);
            }
#pragma unroll
            for (int tn = 0; tn < 4; tn++)
                acc[tn] = __builtin_amdgcn_mfma_f32_16x16x32_bf16(af, bfr[tn], acc[tn], 0, 0, 0);
        }
    }

    for (int tn = 0; tn < 4; tn++)
        for (int r = 0; r < 4; r++) {
            int gm = bm * 64 + wid * 16 + quad * 4 + r;
            int gn = bn * 64 + tn * 16 + l15;
            Cout[(long)gm * 1024 + gn] = acc[tn][r];
        }
}

// ---------------- flash attention: split-K + 4-strip K/V sharing ----------------
// R19: q-rows/wave 32 -> 64 (4 strips sharing K/V fragments) halves wave-kt/CU
// -> LDS ~13us; VALU (~20us) is the ceiling. Block = 256 q-rows, 8 waves
// split-K (waves 0-3 keys [0,1024), 4-7 rest), grid (8,32) = 256 blocks.
// Combine: 2 passes of 128 rows through the dead K/V LDS (34KB overlay).
// R14: max-free softmax (pure exp2, fw sums to 1) => partials add directly.
// R15 V-preload, R14b l-via-MFMA, R8 register-P, R10 K=32 f16 PV packing,
// R13b V half-swap bank fix all retained.
__global__ __launch_bounds__(512, 2)
void attn_kernel(const unsigned short* __restrict__ Q, const unsigned short* __restrict__ Kb,
                 const unsigned short* __restrict__ Vt,
                 unsigned short* __restrict__ O)
{
    // [half][buf][K=0/V=1][64*64 shorts] = 64 KB
    __shared__ __align__(16) unsigned short smem[2][2][2][64 * 64];

    const int tid  = threadIdx.x;
    const int lane = tid & 63, wid = tid >> 6;    // wid in {0..7}
    const int half = wid >> 2, sw = wid & 3;      // key-half, sub-wave
    const int quad = lane >> 4, l15 = lane & 15;
    const int bh = blockIdx.y;
    const int qt = blockIdx.x;                    // 256 q-rows per block, 64 per wave

    const unsigned short* Kg = Kb + (long)bh * S_ * DH_;
    const unsigned short* Vg = Vt + (long)bh * (long)DH_ * S_;

    bf16x8 qf[4][2];
#pragma unroll
    for (int st = 0; st < 4; st++) {
        const unsigned short* Qp = Q + ((long)bh * S_ + qt * 256 + sw * 64 + st * 16 + l15) * DH_ + quad * 8;
        qf[st][0] = *(const bf16x8*)(Qp);
        qf[st][1] = *(const bf16x8*)(Qp + 32);
    }

    // stage absolute tile kt into this half's buffer: 512 chunks K + 512 V,
    // 4 sub-waves x 2 rounds each
    auto issue = [&](int buf, int kt) {
#pragma unroll
        for (int i = 0; i < 2; i++) {
            int base = i * 256 + sw * 64;
            int slot = base + lane;
            int row = slot >> 3, cp = slot & 7;
            int c = cp ^ (row & 7);
            g2l16(Kg + ((long)(kt * 64 + row) * 64 + c * 8), &smem[half][buf][0][base * 8]);
        }
#pragma unroll
        for (int i = 0; i < 2; i++) {
            int base = i * 256 + sw * 64;
            int slot = base + lane;
            int row = slot >> 3, cp = slot & 7;
            int c = cp ^ (row & 7);
            g2l16(Vg + ((long)row * S_ + kt * 64 + c * 8), &smem[half][buf][1][base * 8]);
        }
    };

    f32x4 oacc[4][4] = {};
    f32x4 lacc[4] = {};
    const f16x8 vone = {(_Float16)1.f, (_Float16)1.f, (_Float16)1.f, (_Float16)1.f,
                        (_Float16)1.f, (_Float16)1.f, (_Float16)1.f, (_Float16)1.f};

    const int kt0 = half * 16;                    // 16 tiles per half
    issue(0, kt0);
    __syncthreads();

    const int hf = (((quad & 1) ^ ((l15 >> 3) & 1))) * 4;   // R13b bank fix

    for (int t = 0; t < 16; t++) {
        const int cur = t & 1;
        if (t + 1 < 16) issue(1 - cur, kt0 + t + 1);

        const unsigned short* Kc = &smem[half][cur][0][0];
        const unsigned short* Vc = &smem[half][cur][1][0];

        // ---- S^T tiles: mfma(K_frag, Q_frag) -> [key=quad*4+r][q=l15] ----
        f32x4 sacc[4][4] = {};
#pragma unroll
        for (int kc = 0; kc < 4; kc++) {
            int row = kc * 16 + l15;
            bf16x8 k0 = *(const bf16x8*)(Kc + (row * 8 + (quad       ^ (l15 & 7))) * 8);
            bf16x8 k1 = *(const bf16x8*)(Kc + (row * 8 + ((4 + quad) ^ (l15 & 7))) * 8);
#pragma unroll
            for (int st = 0; st < 4; st++) {
                sacc[st][kc] = __builtin_amdgcn_mfma_f32_16x16x32_bf16(k0, qf[st][0], sacc[st][kc], 0, 0, 0);
                sacc[st][kc] = __builtin_amdgcn_mfma_f32_16x16x32_bf16(k1, qf[st][1], sacc[st][kc], 0, 0, 0);
            }
        }

        // ---- R15: preload ALL V fragments now; LDS drains under exp2 ----
        f16x8 vfr[2][4];
#pragma unroll
        for (int c = 0; c < 2; c++)
#pragma unroll
            for (int dt = 0; dt < 4; dt++) {
                int row = dt * 16 + l15;
                int p0 = (c * 4 +     (quad >> 1)) ^ (l15 & 7);
                int p1 = (c * 4 + 2 + (quad >> 1)) ^ (l15 & 7);
                f16x4 v0 = *(const f16x4*)(Vc + row * 64 + p0 * 8 + hf);
                f16x4 v1 = *(const f16x4*)(Vc + row * 64 + p1 * 8 + hf);
                vfr[c][dt] = __builtin_shufflevector(v0, v1, 0, 1, 2, 3, 4, 5, 6, 7);
            }

        // ---- p = 2^sacc packed into K=32 f16 PV A-fragments (R10 bijection) ----
        f16x8 pk8[4][2];
#pragma unroll
        for (int st = 0; st < 4; st++)
#pragma unroll
            for (int c = 0; c < 2; c++) {
                union { uint4 u; f16x8 v; } pku;
#pragma unroll
                for (int hh = 0; hh < 2; hh++) {
                    float p0 = __builtin_amdgcn_exp2f(sacc[st][2 * c + hh][0]);
                    float p1 = __builtin_amdgcn_exp2f(sacc[st][2 * c + hh][1]);
                    float p2 = __builtin_amdgcn_exp2f(sacc[st][2 * c + hh][2]);
                    float p3 = __builtin_amdgcn_exp2f(sacc[st][2 * c + hh][3]);
                    union { fp16x2 h2; unsigned int u; } a, b;
                    a.h2 = __builtin_amdgcn_cvt_pkrtz(p0, p1);
                    b.h2 = __builtin_amdgcn_cvt_pkrtz(p2, p3);
                    if (hh == 0) { pku.u.x = a.u; pku.u.y = b.u; }
                    else         { pku.u.z = a.u; pku.u.w = b.u; }
                }
                pk8[st][c] = pku.v;
            }

        // ---- O += P V (K=32 f16) all-register; l += P . 1 via MFMA ----
#pragma unroll
        for (int c = 0; c < 2; c++) {
#pragma unroll
            for (int st = 0; st < 4; st++)
                lacc[st] = __builtin_amdgcn_mfma_f32_16x16x32_f16(pk8[st][c], vone, lacc[st], 0, 0, 0);
#pragma unroll
            for (int dt = 0; dt < 4; dt++)
#pragma unroll
                for (int st = 0; st < 4; st++)
                    oacc[st][dt] = __builtin_amdgcn_mfma_f32_16x16x32_f16(pk8[st][c], vfr[c][dt], oacc[st][dt], 0, 0, 0);
        }

        __syncthreads();
    }
    // loop ends with a full barrier: all LDS K/V reads complete -> overlay safe

    // combine overlay over the dead K/V LDS, 2 passes of 128 q-rows:
    // pass p handles strips {2p, 2p+1}; qr' = sw*32 + (st&1)*16 + quad*4 + r
    float* ov = (float*)&smem[0][0][0][0];
    float* lv = ov + 128 * 66;
    int b = bh >> 4, h = bh & 15;

#pragma unroll
    for (int p = 0; p < 2; p++) {
        if (half == 1) {
#pragma unroll
            for (int si = 0; si < 2; si++) {
                int st = 2 * p + si;
#pragma unroll
                for (int dt = 0; dt < 4; dt++)
#pragma unroll
                    for (int r = 0; r < 4; r++) {
                        int qr = sw * 32 + si * 16 + quad * 4 + r;
                        ov[qr * 66 + dt * 16 + l15] = oacc[st][dt][r];
                    }
                if (l15 == 0) {
#pragma unroll
                    for (int r = 0; r < 4; r++)
                        lv[sw * 32 + si * 16 + quad * 4 + r] = lacc[st][r];
                }
            }
        }
        __syncthreads();
        if (half == 0) {
#pragma unroll
            for (int si = 0; si < 2; si++) {
                int st = 2 * p + si;
#pragma unroll
                for (int r = 0; r < 4; r++) {
                    int qr = sw * 32 + si * 16 + quad * 4 + r;
                    float inv = 1.0f / (lacc[st][r] + lv[qr]);
                    int srow = qt * 256 + sw * 64 + st * 16 + quad * 4 + r;
#pragma unroll
                    for (int dt = 0; dt < 4; dt++) {
                        float val = oacc[st][dt][r] + ov[qr * 66 + dt * 16 + l15];
                        O[((long)(b * S_ + srow)) * 1024 + h * DH_ + dt * 16 + l15] = f2bf(val * inv);
                    }
                }
            }
        }
        __syncthreads();
    }
}

// ---------------- launch ----------------

extern "C" void kernel_launch(void* const* d_in, const int* in_sizes, int n_in,
                              void* d_out, int out_size, void* d_ws, size_t ws_size,
                              hipStream_t stream)
{
    const float* x  = (const float*)d_in[0];
    const float* Wq = (const float*)d_in[1];
    const float* Wk = (const float*)d_in[2];
    const float* Wv = (const float*)d_in[3];
    const float* Wo = (const float*)d_in[4];
    const float* fw = (const float*)d_in[5];
    float* out = (float*)d_out;

    char* ws = (char*)d_ws;
    unsigned short* xb    = (unsigned short*)(ws);               // 8 MB   [B*S, D] bf16
    unsigned short* WqkvT = (unsigned short*)(ws + 8388608);     // 6 MB   [3072,1024] bf16
    unsigned short* WoT   = (unsigned short*)(ws + 14680064);    // 2 MB   [1024,1024] bf16
    unsigned short* Qb    = (unsigned short*)(ws + 16777216);    // 8 MB   [B,H,S,64] bf16 (pre-scaled Cq)
    unsigned short* Kb    = (unsigned short*)(ws + 25165824);    // 8 MB   [B,H,S,64] bf16 (pre-scaled fw)
    unsigned short* Vt    = (unsigned short*)(ws + 33554432);    // 8 MB   [B,H,64,S] fp16 (half-swapped)
    unsigned short* Ob    = xb;                                  // alias: xb dead after gemm1

    prep<<<dim3(4096 + 4096), dim3(256), 0, stream>>>(
        x, xb, Wq, Wk, Wv, Wo,
        WqkvT, WqkvT + 1024 * 1024, WqkvT + 2 * 1024 * 1024, WoT);
    gemm128<<<dim3(24, 32), dim3(512), 0, stream>>>(xb, WqkvT, Qb, Kb, Vt, fw);
    attn_kernel<<<dim3(S_ / 256, B_ * H_), dim3(512), 0, stream>>>(Qb, Kb, Vt, Ob);
    gemm_wo<<<dim3(16, 64), dim3(256), 0, stream>>>(Ob, WoT, out);
}

// Round 13
// 181.885 us; speedup vs baseline: 1.0085x; 1.0085x over previous
//
#include <hip/hip_runtime.h>
#include <hip/hip_bf16.h>
#include <stdint.h>

#define B_  2
#define S_  2048
#define D_  1024
#define H_  16
#define DH_ 64

typedef __attribute__((ext_vector_type(8))) __bf16    bf16x8;
typedef __attribute__((ext_vector_type(8))) _Float16  f16x8;
typedef __attribute__((ext_vector_type(4))) _Float16  f16x4;
typedef __attribute__((ext_vector_type(2))) __fp16    fp16x2;   // cvt_pkrtz return type
typedef __attribute__((ext_vector_type(4))) float     f32x4;

__device__ inline unsigned short f2bf(float f) {
    union { float f; uint32_t u; } v; v.f = f;
    uint32_t r = (v.u + 0x7fffu + ((v.u >> 16) & 1u)) >> 16;
    return (unsigned short)r;
}

// async global->LDS, 16B per lane. LDS dest = wave-uniform base + lane*16.
__device__ __forceinline__ void g2l16(const unsigned short* g, unsigned short* l) {
    __builtin_amdgcn_global_load_lds(
        (const __attribute__((address_space(1))) unsigned int*)g,
        (__attribute__((address_space(3))) unsigned int*)l,
        16, 0, 0);
}

// ---------------- merged prep: convert x + transpose weights (R20/R21) ----------------
__global__ void prep(const float* __restrict__ x, unsigned short* __restrict__ xb,
                     const float* __restrict__ s0, const float* __restrict__ s1,
                     const float* __restrict__ s2, const float* __restrict__ s3,
                     unsigned short* __restrict__ d0, unsigned short* __restrict__ d1,
                     unsigned short* __restrict__ d2, unsigned short* __restrict__ d3)
{
    __shared__ float tile[32][33];
    int bid = blockIdx.x, tid = threadIdx.x;
    if (bid < 4096) {
        int i = (bid * 256 + tid) * 4;
        float4 v = *(const float4*)(x + i);
        ushort4 o;
        o.x = f2bf(v.x); o.y = f2bf(v.y); o.z = f2bf(v.z); o.w = f2bf(v.w);
        *(ushort4*)(xb + i) = o;
    } else {
        int tb = bid - 4096;
        int z = tb >> 10, t = tb & 1023;
        int bx = t & 31, by = t >> 5;
        const float* src; unsigned short* dst;
        switch (z) {
            case 0: src = s0; dst = d0; break;
            case 1: src = s1; dst = d1; break;
            case 2: src = s2; dst = d2; break;
            default: src = s3; dst = d3; break;
        }
        int n0 = bx * 32, k0 = by * 32;
        int tx = tid & 31, ty = tid >> 5;   // (32, 8)
        for (int j = 0; j < 32; j += 8)
            tile[ty + j][tx] = src[(long)(k0 + ty + j) * 1024 + n0 + tx];
        __syncthreads();
        for (int j = 0; j < 32; j += 8)
            dst[(long)(n0 + ty + j) * 1024 + k0 + tx] = f2bf(tile[tx][ty + j]);
    }
}

// ---------------- 128x128 MFMA GEMM (gemm0), in-block split-K (R20) + T1 (R22) ----------------
// R22: L2-locality theory. gemm0 stages 393MB from cache over 50us (~7.9TB/s
// aggregate, HBM only 40MB) - all L2/L3-served. Default round-robin dispatch
// spreads consecutive blocks across XCDs -> per-XCD working set = full 6MB B
// panel + scattered A > 4MB L2 -> bulk streams from L3 = the 50us floor.
// Fix: XCD-chunked swizzle (T1). xcd = lin%8 (HW round-robin), each XCD gets
// a 12bn x 8bm rect -> per-XCD set = B 3MB + A 2MB ~ L2-resident.
// R20 split-K: 8 waves, ks=wid>>2 computes its K-half; partials combined
// through dead LDS. R13: Vt half-swap s^((d&8)?4:0) (attn bank fix).
__global__ __launch_bounds__(512, 4)
void gemm128(const unsigned short* __restrict__ A, const unsigned short* __restrict__ Bt,
             unsigned short* __restrict__ Qo, unsigned short* __restrict__ Ko,
             unsigned short* __restrict__ Vt,
             const float* __restrict__ fw)
{
    __shared__ __align__(16) unsigned short Smem[2][128 * 64];   // [0]=A, [1]=B
    unsigned short* As = &Smem[0][0];
    unsigned short* Bs = &Smem[1][0];
    const int tid  = threadIdx.x;
    const int lane = tid & 63, wid = tid >> 6;     // wid in {0..7}
    const int quad = lane >> 4, l15 = lane & 15;
    const int ks   = wid >> 2;                      // K-half this wave computes
    const int wm   = (wid >> 1) & 1, wn = wid & 1;  // 64x64 output quadrant
    // T1 XCD-chunked swizzle: grid (24,32), lin%8 = XCD (HW round-robin).
    // XCD rect: bn in [(xcd&1)*12,+12), bm in [(xcd>>1)*8,+8). Bijective.
    const int lin = blockIdx.y * 24 + blockIdx.x;
    const int xcd = lin & 7, idx = lin >> 3;        // idx in [0,96)
    const int bn = (xcd & 1) * 12 + idx % 12;
    const int bm = (xcd >> 1) * 8 + idx / 12;
    const int K = 1024;
    f32x4 acc[4][4] = {};
    const long Abase = (long)bm * 128 * K;
    const long Bbase = (long)bn * 128 * K;

    for (int k0 = 0; k0 < K; k0 += 64) {
        __syncthreads();
        // A: 1024 chunks of 16B over 8 waves x 2 rounds
#pragma unroll
        for (int i = 0; i < 2; i++) {
            int base = i * 512 + wid * 64;
            int slot = base + lane;
            int row = slot >> 3, cp = slot & 7;
            int c = cp ^ (row & 7);
            g2l16(A + Abase + (long)row * K + k0 + c * 8, &As[base * 8]);
        }
        // B: 1024 chunks
#pragma unroll
        for (int i = 0; i < 2; i++) {
            int base = i * 512 + wid * 64;
            int slot = base + lane;
            int row = slot >> 3, cp = slot & 7;
            int c = cp ^ (row & 7);
            g2l16(Bt + Bbase + (long)row * K + k0 + c * 8, &Bs[base * 8]);
        }
        __syncthreads();
        bf16x8 af[4], bfr[4];
#pragma unroll
        for (int t = 0; t < 4; t++) {
            int ra = wm * 64 + t * 16 + l15;
            af[t]  = *(const bf16x8*)(As + ra * 64 + (((ks * 4 + quad) ^ (l15 & 7))) * 8);
            int rb = wn * 64 + t * 16 + l15;
            bfr[t] = *(const bf16x8*)(Bs + rb * 64 + (((ks * 4 + quad) ^ (l15 & 7))) * 8);
        }
#pragma unroll
        for (int tm = 0; tm < 4; tm++)
#pragma unroll
            for (int tn = 0; tn < 4; tn++)
                acc[tm][tn] = __builtin_amdgcn_mfma_f32_16x16x32_bf16(af[tm], bfr[tn], acc[tm][tn], 0, 0, 0);
    }

    __syncthreads();   // all LDS reads of the last tile complete -> overlay safe

    // combine ks-partials through dead LDS: 4 passes (one per tm), slot =
    // quadrant id (wm*2+wn), layout [4][16][66] fp32 = 16.9 KB.
    float* ov = (float*)&Smem[0][0];
    const int slot = wm * 2 + wn;
    const float Cq = 0.125f * 1.44269504f;   // score scale * log2(e), folded into Q

#pragma unroll
    for (int p = 0; p < 4; p++) {
        if (ks == 1) {
#pragma unroll
            for (int tn = 0; tn < 4; tn++)
#pragma unroll
                for (int r = 0; r < 4; r++)
                    ov[((slot * 16) + quad * 4 + r) * 66 + tn * 16 + l15] = acc[p][tn][r];
        }
        __syncthreads();
        if (ks == 0) {
#pragma unroll
            for (int tn = 0; tn < 4; tn++)
#pragma unroll
                for (int r = 0; r < 4; r++) {
                    float v = acc[p][tn][r] + ov[((slot * 16) + quad * 4 + r) * 66 + tn * 16 + l15];
                    int gm = bm * 128 + wm * 64 + p * 16 + quad * 4 + r;
                    int gn = bn * 128 + wn * 64 + tn * 16 + l15;
                    int b = gm >> 11, s = gm & 2047;
                    if (gn < 1024) {
                        int h = gn >> 6, d = gn & 63;
                        Qo[(((long)(b * H_ + h) * S_ + s) << 6) + d] = f2bf(v * Cq);
                    } else if (gn < 2048) {
                        int g = gn - 1024; int h = g >> 6, d = g & 63;
                        Ko[(((long)(b * H_ + h) * S_ + s) << 6) + d] = f2bf(v * fw[s]);
                    } else {
                        int g = gn - 2048; int h = g >> 6, d = g & 63;
                        union { _Float16 h; unsigned short u; } cv;
                        cv.h = (_Float16)v;                       // V^T stored FP16
                        int sp = s ^ ((d & 8) ? 4 : 0);           // R13 half-swap involution
                        Vt[((long)(b * H_ + h) * DH_ + d) * S_ + sp] = cv.u;
                    }
                }
        }
        __syncthreads();
    }
}

// ---------------- 64x64 MFMA GEMM (gemm1 / Wo projection) + T1 (R22) ----------------
// R18: 64x64 tile, 1024 blocks. R22: XCD rect 8bn x 16bm -> per-XCD set
// B 1MB + A 2MB <= 4MB L2.
__global__ __launch_bounds__(256, 4)
void gemm_wo(const unsigned short* __restrict__ A, const unsigned short* __restrict__ Bt,
             float* __restrict__ Cout)
{
    __shared__ __align__(16) unsigned short As[64 * 64];
    __shared__ __align__(16) unsigned short Bs[64 * 64];
    const int tid  = threadIdx.x;
    const int lane = tid & 63, wid = tid >> 6;
    const int quad = lane >> 4, l15 = lane & 15;
    const int lin = blockIdx.y * 16 + blockIdx.x;
    const int xcd = lin & 7, idx = lin >> 3;        // idx in [0,128)
    const int bn = (xcd & 1) * 8 + (idx & 7);
    const int bm = (xcd >> 1) * 16 + (idx >> 3);
    const int K = 1024;
    f32x4 acc[4] = {};
    const long Abase = (long)bm * 64 * K;
    const long Bbase = (long)bn * 64 * K;

    for (int k0 = 0; k0 < K; k0 += 64) {
        __syncthreads();
#pragma unroll
        for (int i = 0; i < 2; i++) {
            int base = i * 256 + wid * 64;
            int slot = base + lane;
            int row = slot >> 3, cp = slot & 7;
            int c = cp ^ (row & 7);
            g2l16(A + Abase + (long)row * K + k0 + c * 8, &As[base * 8]);
        }
#pragma unroll
        for (int i = 0; i < 2; i++) {
            int base = i * 256 + wid * 64;
            int slot = base + lane;
            int row = slot >> 3, cp = slot & 7;
            int c = cp ^ (row & 7);
            g2l16(Bt + Bbase + (long)row * K + k0 + c * 8, &Bs[base * 8]);
        }
        __syncthreads();
#pragma unroll
        for (int ks = 0; ks < 2; ks++) {
            bf16x8 af, bfr[4];
            {
                int ra = wid * 16 + l15;
                af = *(const bf16x8*)(As + ra * 64 + (((ks * 4 + quad) ^ (l15 & 7))) * 8);
            }
#pragma unroll
            for (int tt = 0; tt < 4; tt++) {
                int rb = tt * 16 + l15;
                bfr[tt] = *(const bf16x8*)(Bs + rb * 64 + (((ks * 4 + quad) ^ (l15 & 7))) * 8);
            }
#pragma unroll
            for (int tn = 0; tn < 4; tn++)
                acc[tn] = __builtin_amdgcn_mfma_f32_16x16x32_bf16(af, bfr[tn], acc[tn], 0, 0, 0);
        }
    }

    for (int tn = 0; tn < 4; tn++)
        for (int r = 0; r < 4; r++) {
            int gm = bm * 64 + wid * 16 + quad * 4 + r;
            int gn = bn * 64 + tn * 16 + l15;
            Cout[(long)gm * 1024 + gn] = acc[tn][r];
        }
}

// ---------------- flash attention: split-K + 4-strip K/V sharing + T1 (R22) ----------------
// R19: 64 q-rows/wave (4 strips sharing K/V fragments); 8-wave split-K.
// R22: XCD swizzle - all 8 qt-blocks of a head pinned to ONE XCD (4 heads/
// XCD = 2MB K/V L2-resident; default round-robin spread them over 8 XCDs =
// 8x L3 re-reads, attn FETCH 71MB).
// R14 max-free softmax partials add directly; R15 V-preload; R14b l-via-MFMA;
// R8 register-P; R10 K=32 f16 PV packing; R13b V half-swap bank fix.
__global__ __launch_bounds__(512, 2)
void attn_kernel(const unsigned short* __restrict__ Q, const unsigned short* __restrict__ Kb,
                 const unsigned short* __restrict__ Vt,
                 unsigned short* __restrict__ O)
{
    // [half][buf][K=0/V=1][64*64 shorts] = 64 KB
    __shared__ __align__(16) unsigned short smem[2][2][2][64 * 64];

    const int tid  = threadIdx.x;
    const int lane = tid & 63, wid = tid >> 6;    // wid in {0..7}
    const int half = wid >> 2, sw = wid & 3;      // key-half, sub-wave
    const int quad = lane >> 4, l15 = lane & 15;
    // T1: grid (8,32) -> lin in [0,256); xcd = lin%8; bh = xcd*4 + idx%4,
    // qt = idx/4. All qt of a head share an XCD. Bijective.
    const int lin = blockIdx.y * 8 + blockIdx.x;
    const int xcd = lin & 7, idx = lin >> 3;      // idx in [0,32)
    const int bh = xcd * 4 + (idx & 3);
    const int qt = idx >> 2;                      // 256 q-rows per block, 64 per wave

    const unsigned short* Kg = Kb + (long)bh * S_ * DH_;
    const unsigned short* Vg = Vt + (long)bh * (long)DH_ * S_;

    bf16x8 qf[4][2];
#pragma unroll
    for (int st = 0; st < 4; st++) {
        const unsigned short* Qp = Q + ((long)bh * S_ + qt * 256 + sw * 64 + st * 16 + l15) * DH_ + quad * 8;
        qf[st][0] = *(const bf16x8*)(Qp);
        qf[st][1] = *(const bf16x8*)(Qp + 32);
    }

    // stage absolute tile kt into this half's buffer: 512 chunks K + 512 V,
    // 4 sub-waves x 2 rounds each
    auto issue = [&](int buf, int kt) {
#pragma unroll
        for (int i = 0; i < 2; i++) {
            int base = i * 256 + sw * 64;
            int slot = base + lane;
            int row = slot >> 3, cp = slot & 7;
            int c = cp ^ (row & 7);
            g2l16(Kg + ((long)(kt * 64 + row) * 64 + c * 8), &smem[half][buf][0][base * 8]);
        }
#pragma unroll
        for (int i = 0; i < 2; i++) {
            int base = i * 256 + sw * 64;
            int slot = base + lane;
            int row = slot >> 3, cp = slot & 7;
            int c = cp ^ (row & 7);
            g2l16(Vg + ((long)row * S_ + kt * 64 + c * 8), &smem[half][buf][1][base * 8]);
        }
    };

    f32x4 oacc[4][4] = {};
    f32x4 lacc[4] = {};
    const f16x8 vone = {(_Float16)1.f, (_Float16)1.f, (_Float16)1.f, (_Float16)1.f,
                        (_Float16)1.f, (_Float16)1.f, (_Float16)1.f, (_Float16)1.f};

    const int kt0 = half * 16;                    // 16 tiles per half
    issue(0, kt0);
    __syncthreads();

    const int hf = (((quad & 1) ^ ((l15 >> 3) & 1))) * 4;   // R13b bank fix

    for (int t = 0; t < 16; t++) {
        const int cur = t & 1;
        if (t + 1 < 16) issue(1 - cur, kt0 + t + 1);

        const unsigned short* Kc = &smem[half][cur][0][0];
        const unsigned short* Vc = &smem[half][cur][1][0];

        // ---- S^T tiles: mfma(K_frag, Q_frag) -> [key=quad*4+r][q=l15] ----
        f32x4 sacc[4][4] = {};
#pragma unroll
        for (int kc = 0; kc < 4; kc++) {
            int row = kc * 16 + l15;
            bf16x8 k0 = *(const bf16x8*)(Kc + (row * 8 + (quad       ^ (l15 & 7))) * 8);
            bf16x8 k1 = *(const bf16x8*)(Kc + (row * 8 + ((4 + quad) ^ (l15 & 7))) * 8);
#pragma unroll
            for (int st = 0; st < 4; st++) {
                sacc[st][kc] = __builtin_amdgcn_mfma_f32_16x16x32_bf16(k0, qf[st][0], sacc[st][kc], 0, 0, 0);
                sacc[st][kc] = __builtin_amdgcn_mfma_f32_16x16x32_bf16(k1, qf[st][1], sacc[st][kc], 0, 0, 0);
            }
        }

        // ---- R15: preload ALL V fragments now; LDS drains under exp2 ----
        f16x8 vfr[2][4];
#pragma unroll
        for (int c = 0; c < 2; c++)
#pragma unroll
            for (int dt = 0; dt < 4; dt++) {
                int row = dt * 16 + l15;
                int p0 = (c * 4 +     (quad >> 1)) ^ (l15 & 7);
                int p1 = (c * 4 + 2 + (quad >> 1)) ^ (l15 & 7);
                f16x4 v0 = *(const f16x4*)(Vc + row * 64 + p0 * 8 + hf);
                f16x4 v1 = *(const f16x4*)(Vc + row * 64 + p1 * 8 + hf);
                vfr[c][dt] = __builtin_shufflevector(v0, v1, 0, 1, 2, 3, 4, 5, 6, 7);
            }

        // ---- p = 2^sacc packed into K=32 f16 PV A-fragments (R10 bijection) ----
        f16x8 pk8[4][2];
#pragma unroll
        for (int st = 0; st < 4; st++)
#pragma unroll
            for (int c = 0; c < 2; c++) {
                union { uint4 u; f16x8 v; } pku;
#pragma unroll
                for (int hh = 0; hh < 2; hh++) {
                    float p0 = __builtin_amdgcn_exp2f(sacc[st][2 * c + hh][0]);
                    float p1 = __builtin_amdgcn_exp2f(sacc[st][2 * c + hh][1]);
                    float p2 = __builtin_amdgcn_exp2f(sacc[st][2 * c + hh][2]);
                    float p3 = __builtin_amdgcn_exp2f(sacc[st][2 * c + hh][3]);
                    union { fp16x2 h2; unsigned int u; } a, b;
                    a.h2 = __builtin_amdgcn_cvt_pkrtz(p0, p1);
                    b.h2 = __builtin_amdgcn_cvt_pkrtz(p2, p3);
                    if (hh == 0) { pku.u.x = a.u; pku.u.y = b.u; }
                    else         { pku.u.z = a.u; pku.u.w = b.u; }
                }
                pk8[st][c] = pku.v;
            }

        // ---- O += P V (K=32 f16) all-register; l += P . 1 via MFMA ----
#pragma unroll
        for (int c = 0; c < 2; c++) {
#pragma unroll
            for (int st = 0; st < 4; st++)
                lacc[st] = __builtin_amdgcn_mfma_f32_16x16x32_f16(pk8[st][c], vone, lacc[st], 0, 0, 0);
#pragma unroll
            for (int dt = 0; dt < 4; dt++)
#pragma unroll
                for (int st = 0; st < 4; st++)
                    oacc[st][dt] = __builtin_amdgcn_mfma_f32_16x16x32_f16(pk8[st][c], vfr[c][dt], oacc[st][dt], 0, 0, 0);
        }

        __syncthreads();
    }
    // loop ends with a full barrier: all LDS K/V reads complete -> overlay safe

    // combine overlay over the dead K/V LDS, 2 passes of 128 q-rows:
    // pass p handles strips {2p, 2p+1}; qr' = sw*32 + (st&1)*16 + quad*4 + r
    float* ov = (float*)&smem[0][0][0][0];
    float* lv = ov + 128 * 66;
    int b = bh >> 4, h = bh & 15;

#pragma unroll
    for (int p = 0; p < 2; p++) {
        if (half == 1) {
#pragma unroll
            for (int si = 0; si < 2; si++) {
                int st = 2 * p + si;
#pragma unroll
                for (int dt = 0; dt < 4; dt++)
#pragma unroll
                    for (int r = 0; r < 4; r++) {
                        int qr = sw * 32 + si * 16 + quad * 4 + r;
                        ov[qr * 66 + dt * 16 + l15] = oacc[st][dt][r];
                    }
                if (l15 == 0) {
#pragma unroll
                    for (int r = 0; r < 4; r++)
                        lv[sw * 32 + si * 16 + quad * 4 + r] = lacc[st][r];
                }
            }
        }
        __syncthreads();
        if (half == 0) {
#pragma unroll
            for (int si = 0; si < 2; si++) {
                int st = 2 * p + si;
#pragma unroll
                for (int r = 0; r < 4; r++) {
                    int qr = sw * 32 + si * 16 + quad * 4 + r;
                    float inv = 1.0f / (lacc[st][r] + lv[qr]);
                    int srow = qt * 256 + sw * 64 + st * 16 + quad * 4 + r;
#pragma unroll
                    for (int dt = 0; dt < 4; dt++) {
                        float val = oacc[st][dt][r] + ov[qr * 66 + dt * 16 + l15];
                        O[((long)(b * S_ + srow)) * 1024 + h * DH_ + dt * 16 + l15] = f2bf(val * inv);
                    }
                }
            }
        }
        __syncthreads();
    }
}

// ---------------- launch ----------------

extern "C" void kernel_launch(void* const* d_in, const int* in_sizes, int n_in,
                              void* d_out, int out_size, void* d_ws, size_t ws_size,
                              hipStream_t stream)
{
    const float* x  = (const float*)d_in[0];
    const float* Wq = (const float*)d_in[1];
    const float* Wk = (const float*)d_in[2];
    const float* Wv = (const float*)d_in[3];
    const float* Wo = (const float*)d_in[4];
    const float* fw = (const float*)d_in[5];
    float* out = (float*)d_out;

    char* ws = (char*)d_ws;
    unsigned short* xb    = (unsigned short*)(ws);               // 8 MB   [B*S, D] bf16
    unsigned short* WqkvT = (unsigned short*)(ws + 8388608);     // 6 MB   [3072,1024] bf16
    unsigned short* WoT   = (unsigned short*)(ws + 14680064);    // 2 MB   [1024,1024] bf16
    unsigned short* Qb    = (unsigned short*)(ws + 16777216);    // 8 MB   [B,H,S,64] bf16 (pre-scaled Cq)
    unsigned short* Kb    = (unsigned short*)(ws + 25165824);    // 8 MB   [B,H,S,64] bf16 (pre-scaled fw)
    unsigned short* Vt    = (unsigned short*)(ws + 33554432);    // 8 MB   [B,H,64,S] fp16 (half-swapped)
    unsigned short* Ob    = xb;                                  // alias: xb dead after gemm1

    prep<<<dim3(4096 + 4096), dim3(256), 0, stream>>>(
        x, xb, Wq, Wk, Wv, Wo,
        WqkvT, WqkvT + 1024 * 1024, WqkvT + 2 * 1024 * 1024, WoT);
    gemm128<<<dim3(24, 32), dim3(512), 0, stream>>>(xb, WqkvT, Qb, Kb, Vt, fw);
    attn_kernel<<<dim3(S_ / 256, B_ * H_), dim3(512), 0, stream>>>(Qb, Kb, Vt, Ob);
    gemm_wo<<<dim3(16, 64), dim3(256), 0, stream>>>(Ob, WoT, out);
}

// Round 14
// 176.363 us; speedup vs baseline: 1.0401x; 1.0313x over previous
//
#include <hip/hip_runtime.h>
#include <hip/hip_bf16.h>
#include <stdint.h>

#define B_  2
#define S_  2048
#define D_  1024
#define H_  16
#define DH_ 64

typedef __attribute__((ext_vector_type(8))) __bf16    bf16x8;
typedef __attribute__((ext_vector_type(8))) _Float16  f16x8;
typedef __attribute__((ext_vector_type(4))) _Float16  f16x4;
typedef __attribute__((ext_vector_type(2))) __fp16    fp16x2;   // cvt_pkrtz return type
typedef __attribute__((ext_vector_type(4))) float     f32x4;

__device__ inline unsigned short f2bf(float f) {
    union { float f; uint32_t u; } v; v.f = f;
    uint32_t r = (v.u + 0x7fffu + ((v.u >> 16) & 1u)) >> 16;
    return (unsigned short)r;
}

// async global->LDS, 16B per lane. LDS dest = wave-uniform base + lane*16.
__device__ __forceinline__ void g2l16(const unsigned short* g, unsigned short* l) {
    __builtin_amdgcn_global_load_lds(
        (const __attribute__((address_space(1))) unsigned int*)g,
        (__attribute__((address_space(3))) unsigned int*)l,
        16, 0, 0);
}

// ---------------- merged prep: convert x + transpose weights (R20/R21) ----------------
__global__ void prep(const float* __restrict__ x, unsigned short* __restrict__ xb,
                     const float* __restrict__ s0, const float* __restrict__ s1,
                     const float* __restrict__ s2, const float* __restrict__ s3,
                     unsigned short* __restrict__ d0, unsigned short* __restrict__ d1,
                     unsigned short* __restrict__ d2, unsigned short* __restrict__ d3)
{
    __shared__ float tile[32][33];
    int bid = blockIdx.x, tid = threadIdx.x;
    if (bid < 4096) {
        int i = (bid * 256 + tid) * 4;
        float4 v = *(const float4*)(x + i);
        ushort4 o;
        o.x = f2bf(v.x); o.y = f2bf(v.y); o.z = f2bf(v.z); o.w = f2bf(v.w);
        *(ushort4*)(xb + i) = o;
    } else {
        int tb = bid - 4096;
        int z = tb >> 10, t = tb & 1023;
        int bx = t & 31, by = t >> 5;
        const float* src; unsigned short* dst;
        switch (z) {
            case 0: src = s0; dst = d0; break;
            case 1: src = s1; dst = d1; break;
            case 2: src = s2; dst = d2; break;
            default: src = s3; dst = d3; break;
        }
        int n0 = bx * 32, k0 = by * 32;
        int tx = tid & 31, ty = tid >> 5;   // (32, 8)
        for (int j = 0; j < 32; j += 8)
            tile[ty + j][tx] = src[(long)(k0 + ty + j) * 1024 + n0 + tx];
        __syncthreads();
        for (int j = 0; j < 32; j += 8)
            dst[(long)(n0 + ty + j) * 1024 + k0 + tx] = f2bf(tile[tx][ty + j]);
    }
}

// ---------------- 256x192 MFMA GEMM (gemm0), byte-traffic reduction (R23) ----------------
// R23 theory: gemm0 is CACHE-TRAFFIC bound. All 128^2 variants stage 393MB
// (A refetch x24, B x32) -> 393MB/50us = 7.9TB/s = L2/L3 service plateau.
// (Evidence: R22 swizzle cut HBM FETCH 40->34MB, dur unchanged; occupancy/
// schedule changes R16-R21 all null.) Fix = FEWER BYTES: 256x192 tile ->
// A 8MB x16 + B 6MB x16 = 229MB (-42%). Grid (16,16) = 256 blocks = 1/CU.
// 1024 thr = 16 waves (4x4), wave owns 64x48 (acc[4][3], ~106 VGPR, lb(1024,4)).
// No split-K combine - each wave owns full K. Single-buffer BK=64, proven
// barrier/swizzle/ds_read pattern. gn scatter branch per-element (2 bn values
// straddle Q/K/V boundaries - correct, mildly divergent).
// T1 XCD swizzle kept: 8bn x 4bm rect/XCD ~ 5MB.
// Scatter -> Q bf16 (PRE-SCALED 0.125*log2e), K bf16 (PRE-SCALED fw[s]),
// Vt[B,H,64,S] fp16, half-swap s^((d&8)?4:0) (R13 attn bank fix).
__global__ __launch_bounds__(1024, 4)
void gemm128(const unsigned short* __restrict__ A, const unsigned short* __restrict__ Bt,
             unsigned short* __restrict__ Qo, unsigned short* __restrict__ Ko,
             unsigned short* __restrict__ Vt,
             const float* __restrict__ fw)
{
    __shared__ __align__(16) unsigned short As[256 * 64];   // 32 KB
    __shared__ __align__(16) unsigned short Bs[192 * 64];   // 24 KB
    const int tid  = threadIdx.x;
    const int lane = tid & 63, wid = tid >> 6;     // wid in {0..15}
    const int quad = lane >> 4, l15 = lane & 15;
    const int wr = wid >> 2, wc = wid & 3;          // 4x4 wave grid
    const int lin = blockIdx.y * 16 + blockIdx.x;
    const int xcd = lin & 7, idx = lin >> 3;        // idx in [0,32)
    const int bn = (xcd & 1) * 8 + (idx & 7);       // [0,16), 192-wide
    const int bm = (xcd >> 1) * 4 + (idx >> 3);     // [0,16), 256-tall
    const int K = 1024;
    f32x4 acc[4][3] = {};
    const long Abase = (long)bm * 256 * K;
    const long Bbase = (long)bn * 192 * K;

    for (int k0 = 0; k0 < K; k0 += 64) {
        __syncthreads();
        // A: 256x64 = 2048 chunks of 16B, 2 rounds x 16 waves
#pragma unroll
        for (int i = 0; i < 2; i++) {
            int base = i * 1024 + wid * 64;
            int slot = base + lane;
            int row = slot >> 3, cp = slot & 7;
            int c = cp ^ (row & 7);
            g2l16(A + Abase + (long)row * K + k0 + c * 8, &As[base * 8]);
        }
        // B: 192x64 = 1536 chunks: full round + half round (waves 0-7)
        {
            int base = wid * 64;
            int slot = base + lane;
            int row = slot >> 3, cp = slot & 7;
            int c = cp ^ (row & 7);
            g2l16(Bt + Bbase + (long)row * K + k0 + c * 8, &Bs[base * 8]);
        }
        if (wid < 8) {
            int base = 1024 + wid * 64;
            int slot = base + lane;
            int row = slot >> 3, cp = slot & 7;
            int c = cp ^ (row & 7);
            g2l16(Bt + Bbase + (long)row * K + k0 + c * 8, &Bs[base * 8]);
        }
        __syncthreads();
#pragma unroll
        for (int ks = 0; ks < 2; ks++) {
            bf16x8 af[4], bfr[3];
            int chunk = ((ks * 4 + quad) ^ (l15 & 7)) * 8;
#pragma unroll
            for (int t = 0; t < 4; t++) {
                int ra = wr * 64 + t * 16 + l15;
                af[t] = *(const bf16x8*)(As + ra * 64 + chunk);
            }
#pragma unroll
            for (int u = 0; u < 3; u++) {
                int rb = wc * 48 + u * 16 + l15;
                bfr[u] = *(const bf16x8*)(Bs + rb * 64 + chunk);
            }
#pragma unroll
            for (int tm = 0; tm < 4; tm++)
#pragma unroll
                for (int tn = 0; tn < 3; tn++)
                    acc[tm][tn] = __builtin_amdgcn_mfma_f32_16x16x32_bf16(af[tm], bfr[tn], acc[tm][tn], 0, 0, 0);
        }
    }

    const float Cq = 0.125f * 1.44269504f;   // score scale * log2(e), folded into Q
    for (int tm = 0; tm < 4; tm++)
        for (int tn = 0; tn < 3; tn++)
            for (int r = 0; r < 4; r++) {
                int gm = bm * 256 + wr * 64 + tm * 16 + quad * 4 + r;
                int gn = bn * 192 + wc * 48 + tn * 16 + l15;
                float v = acc[tm][tn][r];
                int b = gm >> 11, s = gm & 2047;
                if (gn < 1024) {
                    int h = gn >> 6, d = gn & 63;
                    Qo[(((long)(b * H_ + h) * S_ + s) << 6) + d] = f2bf(v * Cq);
                } else if (gn < 2048) {
                    int g = gn - 1024; int h = g >> 6, d = g & 63;
                    Ko[(((long)(b * H_ + h) * S_ + s) << 6) + d] = f2bf(v * fw[s]);
                } else {
                    int g = gn - 2048; int h = g >> 6, d = g & 63;
                    union { _Float16 h; unsigned short u; } cv;
                    cv.h = (_Float16)v;                       // V^T stored FP16
                    int sp = s ^ ((d & 8) ? 4 : 0);           // R13 half-swap involution
                    Vt[((long)(b * H_ + h) * DH_ + d) * S_ + sp] = cv.u;
                }
            }
}

// ---------------- 64x64 MFMA GEMM (gemm1 / Wo projection) + T1 (R22) ----------------
__global__ __launch_bounds__(256, 4)
void gemm_wo(const unsigned short* __restrict__ A, const unsigned short* __restrict__ Bt,
             float* __restrict__ Cout)
{
    __shared__ __align__(16) unsigned short As[64 * 64];
    __shared__ __align__(16) unsigned short Bs[64 * 64];
    const int tid  = threadIdx.x;
    const int lane = tid & 63, wid = tid >> 6;
    const int quad = lane >> 4, l15 = lane & 15;
    const int lin = blockIdx.y * 16 + blockIdx.x;
    const int xcd = lin & 7, idx = lin >> 3;        // idx in [0,128)
    const int bn = (xcd & 1) * 8 + (idx & 7);
    const int bm = (xcd >> 1) * 16 + (idx >> 3);
    const int K = 1024;
    f32x4 acc[4] = {};
    const long Abase = (long)bm * 64 * K;
    const long Bbase = (long)bn * 64 * K;

    for (int k0 = 0; k0 < K; k0 += 64) {
        __syncthreads();
#pragma unroll
        for (int i = 0; i < 2; i++) {
            int base = i * 256 + wid * 64;
            int slot = base + lane;
            int row = slot >> 3, cp = slot & 7;
            int c = cp ^ (row & 7);
            g2l16(A + Abase + (long)row * K + k0 + c * 8, &As[base * 8]);
        }
#pragma unroll
        for (int i = 0; i < 2; i++) {
            int base = i * 256 + wid * 64;
            int slot = base + lane;
            int row = slot >> 3, cp = slot & 7;
            int c = cp ^ (row & 7);
            g2l16(Bt + Bbase + (long)row * K + k0 + c * 8, &Bs[base * 8]);
        }
        __syncthreads();
#pragma unroll
        for (int ks = 0; ks < 2; ks++) {
            bf16x8 af, bfr[4];
            {
                int ra = wid * 16 + l15;
                af = *(const bf16x8*)(As + ra * 64 + (((ks * 4 + quad) ^ (l15 & 7))) * 8);
            }
#pragma unroll
            for (int tt = 0; tt < 4; tt++) {
                int rb = tt * 16 + l15;
                bfr[tt] = *(const bf16x8*)(Bs + rb * 64 + (((ks * 4 + quad) ^ (l15 & 7))) * 8);
            }
#pragma unroll
            for (int tn = 0; tn < 4; tn++)
                acc[tn] = __builtin_amdgcn_mfma_f32_16x16x32_bf16(af, bfr[tn], acc[tn], 0, 0, 0);
        }
    }

    for (int tn = 0; tn < 4; tn++)
        for (int r = 0; r < 4; r++) {
            int gm = bm * 64 + wid * 16 + quad * 4 + r;
            int gn = bn * 64 + tn * 16 + l15;
            Cout[(long)gm * 1024 + gn] = acc[tn][r];
        }
}

// ---------------- flash attention: split-K + 4-strip K/V sharing + T1 (R22) ----------------
// R19: 64 q-rows/wave (4 strips sharing K/V fragments); 8-wave split-K.
// R22: XCD swizzle - all 8 qt-blocks of a head pinned to ONE XCD.
// R14 max-free softmax partials add directly; R15 V-preload; R14b l-via-MFMA;
// R8 register-P; R10 K=32 f16 PV packing; R13b V half-swap bank fix.
__global__ __launch_bounds__(512, 2)
void attn_kernel(const unsigned short* __restrict__ Q, const unsigned short* __restrict__ Kb,
                 const unsigned short* __restrict__ Vt,
                 unsigned short* __restrict__ O)
{
    // [half][buf][K=0/V=1][64*64 shorts] = 64 KB
    __shared__ __align__(16) unsigned short smem[2][2][2][64 * 64];

    const int tid  = threadIdx.x;
    const int lane = tid & 63, wid = tid >> 6;    // wid in {0..7}
    const int half = wid >> 2, sw = wid & 3;      // key-half, sub-wave
    const int quad = lane >> 4, l15 = lane & 15;
    const int lin = blockIdx.y * 8 + blockIdx.x;
    const int xcd = lin & 7, idx = lin >> 3;      // idx in [0,32)
    const int bh = xcd * 4 + (idx & 3);
    const int qt = idx >> 2;                      // 256 q-rows per block, 64 per wave

    const unsigned short* Kg = Kb + (long)bh * S_ * DH_;
    const unsigned short* Vg = Vt + (long)bh * (long)DH_ * S_;

    bf16x8 qf[4][2];
#pragma unroll
    for (int st = 0; st < 4; st++) {
        const unsigned short* Qp = Q + ((long)bh * S_ + qt * 256 + sw * 64 + st * 16 + l15) * DH_ + quad * 8;
        qf[st][0] = *(const bf16x8*)(Qp);
        qf[st][1] = *(const bf16x8*)(Qp + 32);
    }

    auto issue = [&](int buf, int kt) {
#pragma unroll
        for (int i = 0; i < 2; i++) {
            int base = i * 256 + sw * 64;
            int slot = base + lane;
            int row = slot >> 3, cp = slot & 7;
            int c = cp ^ (row & 7);
            g2l16(Kg + ((long)(kt * 64 + row) * 64 + c * 8), &smem[half][buf][0][base * 8]);
        }
#pragma unroll
        for (int i = 0; i < 2; i++) {
            int base = i * 256 + sw * 64;
            int slot = base + lane;
            int row = slot >> 3, cp = slot & 7;
            int c = cp ^ (row & 7);
            g2l16(Vg + ((long)row * S_ + kt * 64 + c * 8), &smem[half][buf][1][base * 8]);
        }
    };

    f32x4 oacc[4][4] = {};
    f32x4 lacc[4] = {};
    const f16x8 vone = {(_Float16)1.f, (_Float16)1.f, (_Float16)1.f, (_Float16)1.f,
                        (_Float16)1.f, (_Float16)1.f, (_Float16)1.f, (_Float16)1.f};

    const int kt0 = half * 16;                    // 16 tiles per half
    issue(0, kt0);
    __syncthreads();

    const int hf = (((quad & 1) ^ ((l15 >> 3) & 1))) * 4;   // R13b bank fix

    for (int t = 0; t < 16; t++) {
        const int cur = t & 1;
        if (t + 1 < 16) issue(1 - cur, kt0 + t + 1);

        const unsigned short* Kc = &smem[half][cur][0][0];
        const unsigned short* Vc = &smem[half][cur][1][0];

        // ---- S^T tiles: mfma(K_frag, Q_frag) -> [key=quad*4+r][q=l15] ----
        f32x4 sacc[4][4] = {};
#pragma unroll
        for (int kc = 0; kc < 4; kc++) {
            int row = kc * 16 + l15;
            bf16x8 k0 = *(const bf16x8*)(Kc + (row * 8 + (quad       ^ (l15 & 7))) * 8);
            bf16x8 k1 = *(const bf16x8*)(Kc + (row * 8 + ((4 + quad) ^ (l15 & 7))) * 8);
#pragma unroll
            for (int st = 0; st < 4; st++) {
                sacc[st][kc] = __builtin_amdgcn_mfma_f32_16x16x32_bf16(k0, qf[st][0], sacc[st][kc], 0, 0, 0);
                sacc[st][kc] = __builtin_amdgcn_mfma_f32_16x16x32_bf16(k1, qf[st][1], sacc[st][kc], 0, 0, 0);
            }
        }

        // ---- R15: preload ALL V fragments now; LDS drains under exp2 ----
        f16x8 vfr[2][4];
#pragma unroll
        for (int c = 0; c < 2; c++)
#pragma unroll
            for (int dt = 0; dt < 4; dt++) {
                int row = dt * 16 + l15;
                int p0 = (c * 4 +     (quad >> 1)) ^ (l15 & 7);
                int p1 = (c * 4 + 2 + (quad >> 1)) ^ (l15 & 7);
                f16x4 v0 = *(const f16x4*)(Vc + row * 64 + p0 * 8 + hf);
                f16x4 v1 = *(const f16x4*)(Vc + row * 64 + p1 * 8 + hf);
                vfr[c][dt] = __builtin_shufflevector(v0, v1, 0, 1, 2, 3, 4, 5, 6, 7);
            }

        // ---- p = 2^sacc packed into K=32 f16 PV A-fragments (R10 bijection) ----
        f16x8 pk8[4][2];
#pragma unroll
        for (int st = 0; st < 4; st++)
#pragma unroll
            for (int c = 0; c < 2; c++) {
                union { uint4 u; f16x8 v; } pku;
#pragma unroll
                for (int hh = 0; hh < 2; hh++) {
                    float p0 = __builtin_amdgcn_exp2f(sacc[st][2 * c + hh][0]);
                    float p1 = __builtin_amdgcn_exp2f(sacc[st][2 * c + hh][1]);
                    float p2 = __builtin_amdgcn_exp2f(sacc[st][2 * c + hh][2]);
                    float p3 = __builtin_amdgcn_exp2f(sacc[st][2 * c + hh][3]);
                    union { fp16x2 h2; unsigned int u; } a, b;
                    a.h2 = __builtin_amdgcn_cvt_pkrtz(p0, p1);
                    b.h2 = __builtin_amdgcn_cvt_pkrtz(p2, p3);
                    if (hh == 0) { pku.u.x = a.u; pku.u.y = b.u; }
                    else         { pku.u.z = a.u; pku.u.w = b.u; }
                }
                pk8[st][c] = pku.v;
            }

        // ---- O += P V (K=32 f16) all-register; l += P . 1 via MFMA ----
#pragma unroll
        for (int c = 0; c < 2; c++) {
#pragma unroll
            for (int st = 0; st < 4; st++)
                lacc[st] = __builtin_amdgcn_mfma_f32_16x16x32_f16(pk8[st][c], vone, lacc[st], 0, 0, 0);
#pragma unroll
            for (int dt = 0; dt < 4; dt++)
#pragma unroll
                for (int st = 0; st < 4; st++)
                    oacc[st][dt] = __builtin_amdgcn_mfma_f32_16x16x32_f16(pk8[st][c], vfr[c][dt], oacc[st][dt], 0, 0, 0);
        }

        __syncthreads();
    }
    // loop ends with a full barrier: all LDS K/V reads complete -> overlay safe

    // combine overlay over the dead K/V LDS, 2 passes of 128 q-rows:
    float* ov = (float*)&smem[0][0][0][0];
    float* lv = ov + 128 * 66;
    int b = bh >> 4, h = bh & 15;

#pragma unroll
    for (int p = 0; p < 2; p++) {
        if (half == 1) {
#pragma unroll
            for (int si = 0; si < 2; si++) {
                int st = 2 * p + si;
#pragma unroll
                for (int dt = 0; dt < 4; dt++)
#pragma unroll
                    for (int r = 0; r < 4; r++) {
                        int qr = sw * 32 + si * 16 + quad * 4 + r;
                        ov[qr * 66 + dt * 16 + l15] = oacc[st][dt][r];
                    }
                if (l15 == 0) {
#pragma unroll
                    for (int r = 0; r < 4; r++)
                        lv[sw * 32 + si * 16 + quad * 4 + r] = lacc[st][r];
                }
            }
        }
        __syncthreads();
        if (half == 0) {
#pragma unroll
            for (int si = 0; si < 2; si++) {
                int st = 2 * p + si;
#pragma unroll
                for (int r = 0; r < 4; r++) {
                    int qr = sw * 32 + si * 16 + quad * 4 + r;
                    float inv = 1.0f / (lacc[st][r] + lv[qr]);
                    int srow = qt * 256 + sw * 64 + st * 16 + quad * 4 + r;
#pragma unroll
                    for (int dt = 0; dt < 4; dt++) {
                        float val = oacc[st][dt][r] + ov[qr * 66 + dt * 16 + l15];
                        O[((long)(b * S_ + srow)) * 1024 + h * DH_ + dt * 16 + l15] = f2bf(val * inv);
                    }
                }
            }
        }
        __syncthreads();
    }
}

// ---------------- launch ----------------

extern "C" void kernel_launch(void* const* d_in, const int* in_sizes, int n_in,
                              void* d_out, int out_size, void* d_ws, size_t ws_size,
                              hipStream_t stream)
{
    const float* x  = (const float*)d_in[0];
    const float* Wq = (const float*)d_in[1];
    const float* Wk = (const float*)d_in[2];
    const float* Wv = (const float*)d_in[3];
    const float* Wo = (const float*)d_in[4];
    const float* fw = (const float*)d_in[5];
    float* out = (float*)d_out;

    char* ws = (char*)d_ws;
    unsigned short* xb    = (unsigned short*)(ws);               // 8 MB   [B*S, D] bf16
    unsigned short* WqkvT = (unsigned short*)(ws + 8388608);     // 6 MB   [3072,1024] bf16
    unsigned short* WoT   = (unsigned short*)(ws + 14680064);    // 2 MB   [1024,1024] bf16
    unsigned short* Qb    = (unsigned short*)(ws + 16777216);    // 8 MB   [B,H,S,64] bf16 (pre-scaled Cq)
    unsigned short* Kb    = (unsigned short*)(ws + 25165824);    // 8 MB   [B,H,S,64] bf16 (pre-scaled fw)
    unsigned short* Vt    = (unsigned short*)(ws + 33554432);    // 8 MB   [B,H,64,S] fp16 (half-swapped)
    unsigned short* Ob    = xb;                                  // alias: xb dead after gemm1

    prep<<<dim3(4096 + 4096), dim3(256), 0, stream>>>(
        x, xb, Wq, Wk, Wv, Wo,
        WqkvT, WqkvT + 1024 * 1024, WqkvT + 2 * 1024 * 1024, WoT);
    gemm128<<<dim3(16, 16), dim3(1024), 0, stream>>>(xb, WqkvT, Qb, Kb, Vt, fw);
    attn_kernel<<<dim3(S_ / 256, B_ * H_), dim3(512), 0, stream>>>(Qb, Kb, Vt, Ob);
    gemm_wo<<<dim3(16, 64), dim3(256), 0, stream>>>(Ob, WoT, out);
}